// Round 9
// baseline (9589.143 us; speedup 1.0000x reference)
//
#include <hip/hip_runtime.h>
#include <math.h>

// 512 rows of length 8192. Power iteration b <- normalize(b - T(x)C(c)b), 100x,
// then sigma = b.(b - TCb); out = mean(|sigma|).
//
// Per iteration: 4 size-8192 FFTs entirely in LDS, one workgroup per row.
// Fusions: mid_junction (fwd-last + spectrum-mult + inv-first, in registers),
// s1_junction (inv-S1 + epilogue + phi-modulate + fwd-S1 per LDS pair).
// Spectra in global fp32 over the input rows (L2/L3-resident, 48 MB total),
// loaded inside mid_junction (float4 consumed immediately).
//
// ROUND 9 KEY CHANGE: amdgpu_waves_per_eu(2,2). Rounds 5-8 all spilled ~17 GB/
// launch regardless of data placement: the body's true peak pressure (y[16]=32
// + breg=16 + ~64 materialized swizzled LDS addresses + twiddle chains +
// scheduler lookahead) exceeds the default 128-VGPR cap. LDS already caps
// residency (64KB/block), so trading occupancy 4->2 waves/SIMD for a 256-VGPR
// budget eliminates scratch entirely. Anti-LICM asm on twiddle bases retained.

#define NN 8192
#define NT 512
#define ROWS 512

__device__ __forceinline__ float2 cadd(float2 a, float2 b){ return make_float2(a.x+b.x, a.y+b.y); }
__device__ __forceinline__ float2 csub(float2 a, float2 b){ return make_float2(a.x-b.x, a.y-b.y); }
__device__ __forceinline__ float2 cmul(float2 a, float2 b){
  return make_float2(fmaf(a.x, b.x, -(a.y*b.y)), fmaf(a.x, b.y, a.y*b.x));
}
__device__ __forceinline__ float2 cscale(float2 a, float s){ return make_float2(a.x*s, a.y*s); }
__device__ __forceinline__ float2 conjf2(float2 a){ return make_float2(a.x, -a.y); }

// XOR swizzle: bank-uniform LDS access in every FFT stage.
__device__ __forceinline__ int ADDR(int e){ return e ^ ((e>>5)&31); }

static constexpr int PM[16] = {0,4,8,12,1,5,9,13,2,6,10,14,3,7,11,15}; // involution

template<bool P> __device__ __forceinline__ constexpr int IX(int i){ return P ? PM[i] : i; }

template<int DIR> // DIR = -1 forward, +1 inverse
__device__ __forceinline__ void dft4(float2& a, float2& b, float2& c, float2& d){
  float2 t0=cadd(a,c), t1=csub(a,c), t2=cadd(b,d), t3=csub(b,d);
  float2 it3 = make_float2((float)(-DIR)*t3.y, (float)DIR*t3.x);
  a = cadd(t0,t2);
  c = csub(t0,t2);
  b = cadd(t1,it3);
  d = csub(t1,it3);
}

template<int DIR, bool P>
__device__ __forceinline__ void dft16i(float2 y[16]){
  dft4<DIR>(y[IX<P>(0)],y[IX<P>(4)],y[IX<P>(8)], y[IX<P>(12)]);
  dft4<DIR>(y[IX<P>(1)],y[IX<P>(5)],y[IX<P>(9)], y[IX<P>(13)]);
  dft4<DIR>(y[IX<P>(2)],y[IX<P>(6)],y[IX<P>(10)],y[IX<P>(14)]);
  dft4<DIR>(y[IX<P>(3)],y[IX<P>(7)],y[IX<P>(11)],y[IX<P>(15)]);
  const float C1=0.92387953251f, S1f=0.38268343236f, C2=0.70710678119f;
  const float D=(float)DIR;
  y[IX<P>(5)]  = cmul(y[IX<P>(5)],  make_float2(C1,  D*S1f));
  y[IX<P>(6)]  = cmul(y[IX<P>(6)],  make_float2(C2,  D*C2));
  y[IX<P>(7)]  = cmul(y[IX<P>(7)],  make_float2(S1f, D*C1));
  y[IX<P>(9)]  = cmul(y[IX<P>(9)],  make_float2(C2,  D*C2));
  y[IX<P>(10)] = cmul(y[IX<P>(10)], make_float2(0.f, D));
  y[IX<P>(11)] = cmul(y[IX<P>(11)], make_float2(-C2, D*C2));
  y[IX<P>(13)] = cmul(y[IX<P>(13)], make_float2(S1f, D*C1));
  y[IX<P>(14)] = cmul(y[IX<P>(14)], make_float2(-C2, D*C2));
  y[IX<P>(15)] = cmul(y[IX<P>(15)], make_float2(-C1, -D*S1f));
  dft4<DIR>(y[IX<P>(0)], y[IX<P>(1)], y[IX<P>(2)], y[IX<P>(3)]);
  dft4<DIR>(y[IX<P>(4)], y[IX<P>(5)], y[IX<P>(6)], y[IX<P>(7)]);
  dft4<DIR>(y[IX<P>(8)], y[IX<P>(9)], y[IX<P>(10)],y[IX<P>(11)]);
  dft4<DIR>(y[IX<P>(12)],y[IX<P>(13)],y[IX<P>(14)],y[IX<P>(15)]);
}

// Middle forward stage: gather, DFT16, twiddle, scatter.
__device__ __forceinline__ void fwd_stage16(float2* buf, int base, int n, int stride, float2 w){
  float2 y[16];
  #pragma unroll
  for(int k=0;k<16;k++) y[k] = buf[ADDR(base + n + stride*k)];
  dft16i<-1,false>(y);
  float2 tw = make_float2(1.f,0.f);
  #pragma unroll
  for(int j=0;j<16;j++){
    buf[ADDR(base + n + stride*j)] = cmul(y[PM[j]], tw);
    tw = cmul(tw, w);
  }
}

// Middle inverse stage.
__device__ __forceinline__ void inv_stage16(float2* buf, int base, int n, int stride, float2 w){
  float2 y[16];
  float2 tw = make_float2(1.f,0.f);
  #pragma unroll
  for(int j=0;j<16;j++){
    y[j] = cmul(buf[ADDR(base + n + stride*j)], tw);
    tw = cmul(tw, w);
  }
  dft16i<1,false>(y);
  #pragma unroll
  for(int i=0;i<16;i++) buf[ADDR(base + n + stride*PM[i])] = y[i];
}

// Plain last forward stage (precompute only): stores slot 16t+j = Spec[j].
__device__ __forceinline__ void fwd_stage_last(float2* buf, int t){
  float2 y[16];
  #pragma unroll
  for(int k=0;k<16;k++) y[k] = buf[ADDR(16*t + k)];
  dft16i<-1,false>(y);
  #pragma unroll
  for(int j=0;j<16;j++) buf[ADDR(16*t + j)] = y[PM[j]];
}

// Fused: fwd-last-stage + spectrum multiply + inv-first-stage, in registers.
// Spectrum loaded HERE, each float4 consumed immediately (no long live range).
// MODE 1: p = 8 float4 = complex G[16t+0..15]. MODE 2: p = 4 float4 = real s[16].
template<int MODE>
__device__ __forceinline__ void mid_junction(float2* buf, int t, const float4* p){
  float2 y[16];
  #pragma unroll
  for(int k=0;k<16;k++) y[k] = buf[ADDR(16*t + k)];
  dft16i<-1,false>(y);
  asm volatile("" ::: "memory");
  if (MODE==1) {
    #pragma unroll
    for(int j4=0;j4<8;j4++){
      float4 a = p[j4];
      y[PM[2*j4]]   = cmul(y[PM[2*j4]],   make_float2(a.x, a.y));
      y[PM[2*j4+1]] = cmul(y[PM[2*j4+1]], make_float2(a.z, a.w));
    }
  } else {
    #pragma unroll
    for(int j4=0;j4<4;j4++){
      float4 a = p[j4];
      y[PM[4*j4]]   = cscale(y[PM[4*j4]],   a.x);
      y[PM[4*j4+1]] = cscale(y[PM[4*j4+1]], a.y);
      y[PM[4*j4+2]] = cscale(y[PM[4*j4+2]], a.z);
      y[PM[4*j4+3]] = cscale(y[PM[4*j4+3]], a.w);
    }
  }
  dft16i<1,true>(y);
  #pragma unroll
  for(int k=0;k<16;k++) buf[ADDR(16*t + k)] = y[k];
}

// S1 (radix-2) from real regs b[j] = v[t+512j].
__device__ __forceinline__ void fwd_s1_real(float2* buf, int t, const float b[16], float2 w1){
  float2 tw = w1;
  const float2 step = make_float2(0.92387953251f, -0.38268343236f); // e^{-i pi/8}
  #pragma unroll
  for(int q=0;q<8;q++){
    int n = t + 512*q;
    float d = b[q] - b[q+8];
    buf[ADDR(n)]      = make_float2(b[q] + b[q+8], 0.f);
    buf[ADDR(n+4096)] = make_float2(d*tw.x, d*tw.y);
    tw = cmul(tw, step);
  }
}

// S1 (radix-2) from complex regs (precompute only).
__device__ __forceinline__ void fwd_s1_cplx(float2* buf, int t, const float2 in[16], float2 w1){
  float2 tw = w1;
  const float2 step = make_float2(0.92387953251f, -0.38268343236f);
  #pragma unroll
  for(int q=0;q<8;q++){
    int n = t + 512*q;
    buf[ADDR(n)]      = cadd(in[q], in[q+8]);
    buf[ADDR(n+4096)] = cmul(csub(in[q], in[q+8]), tw);
    tw = cmul(tw, step);
  }
}

// Fused: inv-S1 (end FFT1-IFFT) + epilogue1 + phi-modulate + fwd-S1 (FFT2).
template<bool SIGMA>
__device__ __forceinline__ void s1_junction(float2* buf, int t, float breg[16], float& loc,
                                            float2 w1, float pc, float ps, float sc1){
  float2 twi = conjf2(w1), twf = w1;
  const float2 stepi = make_float2(0.92387953251f,  0.38268343236f);
  const float2 stepf = make_float2(0.92387953251f, -0.38268343236f);
  float2 ph = make_float2(pc, ps);
  const float2 phstep = make_float2(0.98078528040f, -0.19509032202f); // e^{-i pi/16}
  #pragma unroll
  for(int q=0;q<8;q++){
    int n = t + 512*q;
    float2 z0 = buf[ADDR(n)];
    float2 z1 = cmul(buf[ADDR(n+4096)], twi);
    float2 zn = cscale(cadd(z0,z1), sc1);   // u_n + i*hx1_n
    float2 zm = cscale(csub(z0,z1), sc1);   // u_m + i*hx1_m
    if (SIGMA) {
      loc += breg[q]*(breg[q]-zn.y) + breg[q+8]*(breg[q+8]-zm.y);
    } else {
      breg[q]   -= zn.y;
      breg[q+8] -= zm.y;
    }
    float2 vn = make_float2(zn.x*ph.x,  zn.x*ph.y);
    float2 vm = make_float2(zm.x*ph.y, -zm.x*ph.x);
    buf[ADDR(n)]      = cadd(vn, vm);
    buf[ADDR(n+4096)] = cmul(csub(vn, vm), twf);
    twi = cmul(twi, stepi); twf = cmul(twf, stepf); ph = cmul(ph, phstep);
  }
}

// Fused: inv-S1 (end FFT2-IFFT) + epilogue2.
template<bool SIGMA>
__device__ __forceinline__ void s1_final(float2* buf, int t, float breg[16], float& loc,
                                         float2 w1, float pc, float ps, float sc2){
  float2 twi = conjf2(w1);
  const float2 stepi = make_float2(0.92387953251f, 0.38268343236f);
  float2 ph = make_float2(pc, ps);
  const float2 phstep = make_float2(0.98078528040f, -0.19509032202f);
  #pragma unroll
  for(int q=0;q<8;q++){
    int n = t + 512*q;
    float2 z0 = buf[ADDR(n)];
    float2 z1 = cmul(buf[ADDR(n+4096)], twi);
    float2 yn = cscale(cadd(z0,z1), sc2);
    float2 ym = cscale(csub(z0,z1), sc2);
    float qn = fmaf(ph.x, yn.x,  ph.y*yn.y);     // Re(conj(ph)*yn)
    float qm = fmaf(ph.y, ym.x, -ph.x*ym.y);     // Re(i*conj(ph)*ym)
    if (SIGMA) {
      loc -= breg[q]*qn + breg[q+8]*qm;
    } else {
      float bn = breg[q]   - qn; breg[q]   = bn; loc = fmaf(bn,bn,loc);
      bn       = breg[q+8] - qm; breg[q+8] = bn; loc = fmaf(bn,bn,loc);
    }
    twi = cmul(twi, stepi); ph = cmul(ph, phstep);
  }
}

// One full iteration body (4 FFTs + epilogues + block reduction); returns tot.
template<bool SIGMA>
__device__ __forceinline__ float iterate(float2* buf, float* red, int t, float breg[16],
                                         float2 w1, float2 w2, float2 w3, float pc, float ps,
                                         const float4* gptr, const float4* sptr){
  const float sc1 = 1.f/8192.f, sc2 = 1.f/8192.f;
  float loc = 0.f;

  fwd_s1_real(buf, t, breg, w1);
  __syncthreads();
  fwd_stage16(buf, (t>>8)*4096, t&255, 256, w2);
  __syncthreads();
  fwd_stage16(buf, (t>>4)*256,  t&15,  16,  w3);
  __syncthreads();
  mid_junction<1>(buf, t, gptr);                     // *G (loaded in-place)
  __syncthreads();
  inv_stage16(buf, (t>>4)*256,  t&15,  16,  conjf2(w3));
  __syncthreads();
  inv_stage16(buf, (t>>8)*4096, t&255, 256, conjf2(w2));
  __syncthreads();
  s1_junction<SIGMA>(buf, t, breg, loc, w1, pc, ps, sc1);
  __syncthreads();
  fwd_stage16(buf, (t>>8)*4096, t&255, 256, w2);
  __syncthreads();
  fwd_stage16(buf, (t>>4)*256,  t&15,  16,  w3);
  __syncthreads();
  mid_junction<2>(buf, t, sptr);                     // *0.5*S2o (loaded in-place)
  __syncthreads();
  inv_stage16(buf, (t>>4)*256,  t&15,  16,  conjf2(w3));
  __syncthreads();
  inv_stage16(buf, (t>>8)*4096, t&255, 256, conjf2(w2));
  __syncthreads();
  s1_final<SIGMA>(buf, t, breg, loc, w1, pc, ps, sc2);

  __syncthreads();
  #pragma unroll
  for(int off=32; off; off>>=1) loc += __shfl_down(loc, off, 64);
  if((t&63)==0) red[t>>6] = loc;
  __syncthreads();
  float tot = 0.f;
  #pragma unroll
  for(int w=0;w<8;w++) tot += red[w];
  __syncthreads();
  return tot;
}

__global__ void msvl_zero(float* out){ out[0] = 0.f; }

__global__ void __launch_bounds__(512) __attribute__((amdgpu_waves_per_eu(2, 2)))
msvl_main(float* x, float* circ, float* b0, float* out){
  __shared__ float2 buf[NN];   // 64 KB
  __shared__ float red[8];
  const int t = threadIdx.x;
  const int row = blockIdx.x;

  float* xrow = x    + (size_t)row * NN;
  float* crow = circ + (size_t)row * NN;
  float* brow = b0   + (size_t)row * NN;

  // Per-thread twiddle bases (8 scalars; redefined opaquely in-loop vs LICM).
  float s1v,c1v,s2v,c2v,s3v,c3v,psv,pcv;
  __sincosf(-6.28318530718f*(float)t/8192.f,        &s1v,&c1v);
  __sincosf(-6.28318530718f*(float)(t&255)/4096.f,  &s2v,&c2v);
  __sincosf(-6.28318530718f*(float)(t&15)/256.f,    &s3v,&c3v);
  __sincosf(-3.14159265359f*(float)t/8192.f,        &psv,&pcv);
  const float2 phstep = make_float2(0.98078528040f, -0.19509032202f);

  float breg[16];

  // --- init: b = b0 / ||b0||  (precedes spectra overwrite of brow) ----------
  {
    float nrm = 0.f;
    #pragma unroll
    for(int j=0;j<16;j++){ float v = brow[t+512*j]; breg[j]=v; nrm = fmaf(v,v,nrm); }
    #pragma unroll
    for(int off=32; off; off>>=1) nrm += __shfl_down(nrm, off, 64);
    if((t&63)==0) red[t>>6] = nrm;
    __syncthreads();
    float tot = 0.f;
    #pragma unroll
    for(int w=0;w<8;w++) tot += red[w];
    float isc = rsqrtf(tot);
    #pragma unroll
    for(int j=0;j<16;j++) breg[j] *= isc;
  }

  // --- precompute spectra (3 forward FFTs) -> global (over input rows) ------
  {
    const float2 w1 = make_float2(c1v,s1v), w2 = make_float2(c2v,s2v), w3 = make_float2(c3v,s3v);
    float fj[16], dj[16];
    #pragma unroll
    for(int j=0;j<16;j++){
      int n = t + 512*j;
      float xn = xrow[n];
      float xr = (n==0) ? 0.f : xrow[NN - n];
      fj[j] = xn + xr;
      dj[j] = xn - xr;
    }
    // FFT(f) -> 0.5*S2e at slots 16t+j
    fwd_s1_real(buf, t, fj, w1);
    __syncthreads();
    fwd_stage16(buf, (t>>8)*4096, t&255, 256, w2);
    __syncthreads();
    fwd_stage16(buf, (t>>4)*256,  t&15,  16,  w3);
    __syncthreads();
    fwd_stage_last(buf, t);
    __syncthreads();
    float se[16];
    #pragma unroll
    for(int j=0;j<16;j++) se[j] = 0.5f * buf[ADDR(16*t+j)].x;
    __syncthreads();
    // FFT(d*phi) -> 0.5*S2o -> brow
    {
      float2 ph = make_float2(pcv, psv);
      float2 tmp[16];
      #pragma unroll
      for(int j=0;j<16;j++){ tmp[j] = make_float2(dj[j]*ph.x, dj[j]*ph.y); ph = cmul(ph, phstep); }
      fwd_s1_cplx(buf, t, tmp, w1);
    }
    __syncthreads();
    fwd_stage16(buf, (t>>8)*4096, t&255, 256, w2);
    __syncthreads();
    fwd_stage16(buf, (t>>4)*256,  t&15,  16,  w3);
    __syncthreads();
    fwd_stage_last(buf, t);
    __syncthreads();
    #pragma unroll
    for(int j=0;j<16;j++) brow[16*t+j] = 0.5f * buf[ADDR(16*t+j)].x;
    __syncthreads();
    // FFT(c) -> Fc; G = Fc*(1 + i*se) -> xrow/crow
    #pragma unroll
    for(int j=0;j<16;j++) fj[j] = crow[t+512*j];
    fwd_s1_real(buf, t, fj, w1);
    __syncthreads();
    fwd_stage16(buf, (t>>8)*4096, t&255, 256, w2);
    __syncthreads();
    fwd_stage16(buf, (t>>4)*256,  t&15,  16,  w3);
    __syncthreads();
    fwd_stage_last(buf, t);
    __syncthreads();
    if (t < 256) {
      float2* gdst = (float2*)xrow;
      #pragma unroll
      for(int j=0;j<16;j++){
        int e = 16*t + j;
        float2 fc = buf[ADDR(e)];
        gdst[e] = make_float2(fmaf(-fc.y, se[j], fc.x), fmaf(fc.x, se[j], fc.y));
      }
    } else {
      float2* gdst = (float2*)crow;
      #pragma unroll
      for(int j=0;j<16;j++){
        int e = 16*t + j;
        float2 fc = buf[ADDR(e)];
        gdst[e - 4096] = make_float2(fmaf(-fc.y, se[j], fc.x), fmaf(fc.x, se[j], fc.y));
      }
    }
    __syncthreads();
  }

  const float4* gptr = (t < 256) ? (const float4*)((const float2*)xrow + 16*t)
                                 : (const float4*)((const float2*)crow + (16*t - 4096));
  const float4* sptr = (const float4*)(brow + 16*t);

  // --- 100 power iterations (rolled) ----------------------------------------
  #pragma clang loop unroll(disable)
  for(int iter=0; iter<100; ++iter){
    // Opaque redefinition: kills LICM hoisting/spilling of all twiddle chains.
    asm volatile("" : "+v"(c1v), "+v"(s1v), "+v"(c2v), "+v"(s2v),
                      "+v"(c3v), "+v"(s3v), "+v"(pcv), "+v"(psv));
    const float2 w1 = make_float2(c1v,s1v), w2 = make_float2(c2v,s2v), w3 = make_float2(c3v,s3v);
    float tot = iterate<false>(buf, red, t, breg, w1, w2, w3, pcv, psv, gptr, sptr);
    float s = rsqrtf(tot);
    #pragma unroll
    for(int j=0;j<16;j++) breg[j] *= s;
  }

  // --- final matvec for sigma ------------------------------------------------
  {
    asm volatile("" : "+v"(c1v), "+v"(s1v), "+v"(c2v), "+v"(s2v),
                      "+v"(c3v), "+v"(s3v), "+v"(pcv), "+v"(psv));
    const float2 w1 = make_float2(c1v,s1v), w2 = make_float2(c2v,s2v), w3 = make_float2(c3v,s3v);
    float tot = iterate<true>(buf, red, t, breg, w1, w2, w3, pcv, psv, gptr, sptr);
    if(t == 0) atomicAdd(out, fabsf(tot) * (1.f/512.f));
  }
}

extern "C" void kernel_launch(void* const* d_in, const int* in_sizes, int n_in,
                              void* d_out, int out_size, void* d_ws, size_t ws_size,
                              hipStream_t stream) {
  float* x    = (float*)d_in[0];
  float* circ = (float*)d_in[1];
  float* b0   = (float*)d_in[2];
  float* out  = (float*)d_out;

  hipLaunchKernelGGL(msvl_zero, dim3(1), dim3(1), 0, stream, out);
  hipLaunchKernelGGL(msvl_main, dim3(ROWS), dim3(NT), 0, stream,
                     x, circ, b0, out);
}

// Round 10
// 8107.159 us; speedup vs baseline: 1.1828x; 1.1828x over previous
//
#include <hip/hip_runtime.h>
#include <math.h>

// 512 rows of length 8192. Power iteration b <- normalize(b - T(x)C(c)b), 100x,
// then sigma = b.(b - TCb); out = mean(|sigma|).
//
// Per iteration: 4 size-8192 FFTs entirely in LDS, one workgroup per row.
// Fusions: mid_junction (fwd-last + spectrum-mult + inv-first, in registers),
// s1_junction (inv-S1 + epilogue + phi-modulate + fwd-S1 per LDS pair).
// Spectra in global fp32 over the input rows, loaded inside mid_junction.
//
// ROUND 10 KEY CHANGE: LDS layout switched from XOR swizzle (non-affine ->
// 16 materialized address VGPRs per stage pattern, ~64 loop-invariant regs ->
// the 17 GB/launch scratch spills of rounds 5-9) to classic FFT padding
//   a(e) = e + (e>>4)   (one float2 pad per 16)
// Every stage's accesses become base + affine-stride*k -> single address VGPR
// + ds imm offsets. Bank check (b64): each stage hits every bank-pair exactly
// 4x across 64 lanes = the b64 floor -> conflict-free, same as the swizzle.
// LDS 69,664 B -> still 2 blocks/CU.
//
// Padded bases (derived exactly, no runtime >>4 of sums):
//   S1:     a = t+(t>>4) + 544q, mirror +4352
//   stage2: a = (t>>8)*4352 + m+(m>>4) + 272k,  m = t&255
//   stage3: a = (t>>4)*272 + (t&15) + 17k
//   mid:    a = 17t + k

#define NN 8192
#define NT 512
#define ROWS 512
#define BUFSZ 8704   // 8192 + 512 pad (float2)

__device__ __forceinline__ float2 cadd(float2 a, float2 b){ return make_float2(a.x+b.x, a.y+b.y); }
__device__ __forceinline__ float2 csub(float2 a, float2 b){ return make_float2(a.x-b.x, a.y-b.y); }
__device__ __forceinline__ float2 cmul(float2 a, float2 b){
  return make_float2(fmaf(a.x, b.x, -(a.y*b.y)), fmaf(a.x, b.y, a.y*b.x));
}
__device__ __forceinline__ float2 cscale(float2 a, float s){ return make_float2(a.x*s, a.y*s); }
__device__ __forceinline__ float2 conjf2(float2 a){ return make_float2(a.x, -a.y); }

static constexpr int PM[16] = {0,4,8,12,1,5,9,13,2,6,10,14,3,7,11,15}; // involution

template<bool P> __device__ __forceinline__ constexpr int IX(int i){ return P ? PM[i] : i; }

template<int DIR> // DIR = -1 forward, +1 inverse
__device__ __forceinline__ void dft4(float2& a, float2& b, float2& c, float2& d){
  float2 t0=cadd(a,c), t1=csub(a,c), t2=cadd(b,d), t3=csub(b,d);
  float2 it3 = make_float2((float)(-DIR)*t3.y, (float)DIR*t3.x);
  a = cadd(t0,t2);
  c = csub(t0,t2);
  b = cadd(t1,it3);
  d = csub(t1,it3);
}

template<int DIR, bool P>
__device__ __forceinline__ void dft16i(float2 y[16]){
  dft4<DIR>(y[IX<P>(0)],y[IX<P>(4)],y[IX<P>(8)], y[IX<P>(12)]);
  dft4<DIR>(y[IX<P>(1)],y[IX<P>(5)],y[IX<P>(9)], y[IX<P>(13)]);
  dft4<DIR>(y[IX<P>(2)],y[IX<P>(6)],y[IX<P>(10)],y[IX<P>(14)]);
  dft4<DIR>(y[IX<P>(3)],y[IX<P>(7)],y[IX<P>(11)],y[IX<P>(15)]);
  const float C1=0.92387953251f, S1f=0.38268343236f, C2=0.70710678119f;
  const float D=(float)DIR;
  y[IX<P>(5)]  = cmul(y[IX<P>(5)],  make_float2(C1,  D*S1f));
  y[IX<P>(6)]  = cmul(y[IX<P>(6)],  make_float2(C2,  D*C2));
  y[IX<P>(7)]  = cmul(y[IX<P>(7)],  make_float2(S1f, D*C1));
  y[IX<P>(9)]  = cmul(y[IX<P>(9)],  make_float2(C2,  D*C2));
  y[IX<P>(10)] = cmul(y[IX<P>(10)], make_float2(0.f, D));
  y[IX<P>(11)] = cmul(y[IX<P>(11)], make_float2(-C2, D*C2));
  y[IX<P>(13)] = cmul(y[IX<P>(13)], make_float2(S1f, D*C1));
  y[IX<P>(14)] = cmul(y[IX<P>(14)], make_float2(-C2, D*C2));
  y[IX<P>(15)] = cmul(y[IX<P>(15)], make_float2(-C1, -D*S1f));
  dft4<DIR>(y[IX<P>(0)], y[IX<P>(1)], y[IX<P>(2)], y[IX<P>(3)]);
  dft4<DIR>(y[IX<P>(4)], y[IX<P>(5)], y[IX<P>(6)], y[IX<P>(7)]);
  dft4<DIR>(y[IX<P>(8)], y[IX<P>(9)], y[IX<P>(10)],y[IX<P>(11)]);
  dft4<DIR>(y[IX<P>(12)],y[IX<P>(13)],y[IX<P>(14)],y[IX<P>(15)]);
}

// Middle forward stage: buf[a0 + st*k], affine -> imm offsets.
__device__ __forceinline__ void fwd_stage16(float2* buf, int a0, int st, float2 w){
  float2 y[16];
  #pragma unroll
  for(int k=0;k<16;k++) y[k] = buf[a0 + st*k];
  dft16i<-1,false>(y);
  float2 tw = make_float2(1.f,0.f);
  #pragma unroll
  for(int j=0;j<16;j++){
    buf[a0 + st*j] = cmul(y[PM[j]], tw);
    tw = cmul(tw, w);
  }
}

// Middle inverse stage.
__device__ __forceinline__ void inv_stage16(float2* buf, int a0, int st, float2 w){
  float2 y[16];
  float2 tw = make_float2(1.f,0.f);
  #pragma unroll
  for(int j=0;j<16;j++){
    y[j] = cmul(buf[a0 + st*j], tw);
    tw = cmul(tw, w);
  }
  dft16i<1,false>(y);
  #pragma unroll
  for(int i=0;i<16;i++) buf[a0 + st*PM[i]] = y[i];
}

// Plain last forward stage (precompute only): stores slot aM+j = Spec[j].
__device__ __forceinline__ void fwd_stage_last(float2* buf, int aM){
  float2 y[16];
  #pragma unroll
  for(int k=0;k<16;k++) y[k] = buf[aM + k];
  dft16i<-1,false>(y);
  #pragma unroll
  for(int j=0;j<16;j++) buf[aM + j] = y[PM[j]];
}

// Fused: fwd-last-stage + spectrum multiply + inv-first-stage, in registers.
// MODE 1: p = 8 float4 = complex G[16t+0..15]. MODE 2: p = 4 float4 = real s[16].
template<int MODE>
__device__ __forceinline__ void mid_junction(float2* buf, int aM, const float4* p){
  float2 y[16];
  #pragma unroll
  for(int k=0;k<16;k++) y[k] = buf[aM + k];
  dft16i<-1,false>(y);
  asm volatile("" ::: "memory");
  if (MODE==1) {
    #pragma unroll
    for(int j4=0;j4<8;j4++){
      float4 a = p[j4];
      y[PM[2*j4]]   = cmul(y[PM[2*j4]],   make_float2(a.x, a.y));
      y[PM[2*j4+1]] = cmul(y[PM[2*j4+1]], make_float2(a.z, a.w));
    }
  } else {
    #pragma unroll
    for(int j4=0;j4<4;j4++){
      float4 a = p[j4];
      y[PM[4*j4]]   = cscale(y[PM[4*j4]],   a.x);
      y[PM[4*j4+1]] = cscale(y[PM[4*j4+1]], a.y);
      y[PM[4*j4+2]] = cscale(y[PM[4*j4+2]], a.z);
      y[PM[4*j4+3]] = cscale(y[PM[4*j4+3]], a.w);
    }
  }
  dft16i<1,true>(y);
  #pragma unroll
  for(int k=0;k<16;k++) buf[aM + k] = y[k];
}

// S1 (radix-2) from real regs b[j] = v[t+512j]. aS1 = t+(t>>4).
__device__ __forceinline__ void fwd_s1_real(float2* buf, int aS1, const float b[16], float2 w1){
  float2 tw = w1;
  const float2 step = make_float2(0.92387953251f, -0.38268343236f); // e^{-i pi/8}
  #pragma unroll
  for(int q=0;q<8;q++){
    int a = aS1 + 544*q;
    float d = b[q] - b[q+8];
    buf[a]        = make_float2(b[q] + b[q+8], 0.f);
    buf[a + 4352] = make_float2(d*tw.x, d*tw.y);
    tw = cmul(tw, step);
  }
}

// S1 (radix-2) from complex regs (precompute only).
__device__ __forceinline__ void fwd_s1_cplx(float2* buf, int aS1, const float2 in[16], float2 w1){
  float2 tw = w1;
  const float2 step = make_float2(0.92387953251f, -0.38268343236f);
  #pragma unroll
  for(int q=0;q<8;q++){
    int a = aS1 + 544*q;
    buf[a]        = cadd(in[q], in[q+8]);
    buf[a + 4352] = cmul(csub(in[q], in[q+8]), tw);
    tw = cmul(tw, step);
  }
}

// Fused: inv-S1 (end FFT1-IFFT) + epilogue1 + phi-modulate + fwd-S1 (FFT2).
template<bool SIGMA>
__device__ __forceinline__ void s1_junction(float2* buf, int aS1, float breg[16], float& loc,
                                            float2 w1, float pc, float ps, float sc1){
  float2 twi = conjf2(w1), twf = w1;
  const float2 stepi = make_float2(0.92387953251f,  0.38268343236f);
  const float2 stepf = make_float2(0.92387953251f, -0.38268343236f);
  float2 ph = make_float2(pc, ps);
  const float2 phstep = make_float2(0.98078528040f, -0.19509032202f); // e^{-i pi/16}
  #pragma unroll
  for(int q=0;q<8;q++){
    int a = aS1 + 544*q;
    float2 z0 = buf[a];
    float2 z1 = cmul(buf[a + 4352], twi);
    float2 zn = cscale(cadd(z0,z1), sc1);   // u_n + i*hx1_n
    float2 zm = cscale(csub(z0,z1), sc1);   // u_m + i*hx1_m
    if (SIGMA) {
      loc += breg[q]*(breg[q]-zn.y) + breg[q+8]*(breg[q+8]-zm.y);
    } else {
      breg[q]   -= zn.y;
      breg[q+8] -= zm.y;
    }
    float2 vn = make_float2(zn.x*ph.x,  zn.x*ph.y);
    float2 vm = make_float2(zm.x*ph.y, -zm.x*ph.x);
    buf[a]        = cadd(vn, vm);
    buf[a + 4352] = cmul(csub(vn, vm), twf);
    twi = cmul(twi, stepi); twf = cmul(twf, stepf); ph = cmul(ph, phstep);
  }
}

// Fused: inv-S1 (end FFT2-IFFT) + epilogue2.
template<bool SIGMA>
__device__ __forceinline__ void s1_final(float2* buf, int aS1, float breg[16], float& loc,
                                         float2 w1, float pc, float ps, float sc2){
  float2 twi = conjf2(w1);
  const float2 stepi = make_float2(0.92387953251f, 0.38268343236f);
  float2 ph = make_float2(pc, ps);
  const float2 phstep = make_float2(0.98078528040f, -0.19509032202f);
  #pragma unroll
  for(int q=0;q<8;q++){
    int a = aS1 + 544*q;
    float2 z0 = buf[a];
    float2 z1 = cmul(buf[a + 4352], twi);
    float2 yn = cscale(cadd(z0,z1), sc2);
    float2 ym = cscale(csub(z0,z1), sc2);
    float qn = fmaf(ph.x, yn.x,  ph.y*yn.y);     // Re(conj(ph)*yn)
    float qm = fmaf(ph.y, ym.x, -ph.x*ym.y);     // Re(i*conj(ph)*ym)
    if (SIGMA) {
      loc -= breg[q]*qn + breg[q+8]*qm;
    } else {
      float bn = breg[q]   - qn; breg[q]   = bn; loc = fmaf(bn,bn,loc);
      bn       = breg[q+8] - qm; breg[q+8] = bn; loc = fmaf(bn,bn,loc);
    }
    twi = cmul(twi, stepi); ph = cmul(ph, phstep);
  }
}

// One full iteration body (4 FFTs + epilogues + block reduction); returns tot.
template<bool SIGMA>
__device__ __forceinline__ float iterate(float2* buf, float* red, int t, float breg[16],
                                         int aS1, int a2, int a3, int aM,
                                         float2 w1, float2 w2, float2 w3, float pc, float ps,
                                         const float4* gptr, const float4* sptr){
  const float sc1 = 1.f/8192.f, sc2 = 1.f/8192.f;
  float loc = 0.f;

  fwd_s1_real(buf, aS1, breg, w1);
  __syncthreads();
  fwd_stage16(buf, a2, 272, w2);
  __syncthreads();
  fwd_stage16(buf, a3, 17,  w3);
  __syncthreads();
  mid_junction<1>(buf, aM, gptr);                    // *G (loaded in-place)
  __syncthreads();
  inv_stage16(buf, a3, 17,  conjf2(w3));
  __syncthreads();
  inv_stage16(buf, a2, 272, conjf2(w2));
  __syncthreads();
  s1_junction<SIGMA>(buf, aS1, breg, loc, w1, pc, ps, sc1);
  __syncthreads();
  fwd_stage16(buf, a2, 272, w2);
  __syncthreads();
  fwd_stage16(buf, a3, 17,  w3);
  __syncthreads();
  mid_junction<2>(buf, aM, sptr);                    // *0.5*S2o (loaded in-place)
  __syncthreads();
  inv_stage16(buf, a3, 17,  conjf2(w3));
  __syncthreads();
  inv_stage16(buf, a2, 272, conjf2(w2));
  __syncthreads();
  s1_final<SIGMA>(buf, aS1, breg, loc, w1, pc, ps, sc2);

  __syncthreads();
  #pragma unroll
  for(int off=32; off; off>>=1) loc += __shfl_down(loc, off, 64);
  if((t&63)==0) red[t>>6] = loc;
  __syncthreads();
  float tot = 0.f;
  #pragma unroll
  for(int w=0;w<8;w++) tot += red[w];
  __syncthreads();
  return tot;
}

__global__ void msvl_zero(float* out){ out[0] = 0.f; }

__global__ void __launch_bounds__(512)
msvl_main(float* x, float* circ, float* b0, float* out){
  __shared__ float2 buf[BUFSZ];   // 69,632 B -> 2 blocks/CU
  __shared__ float red[8];
  const int t = threadIdx.x;
  const int row = blockIdx.x;

  float* xrow = x    + (size_t)row * NN;
  float* crow = circ + (size_t)row * NN;
  float* brow = b0   + (size_t)row * NN;

  // Padded-layout per-thread bases (iteration-invariant, 4 small ints).
  const int aS1 = t + (t>>4);
  const int a2  = (t>>8)*4352 + (t&255) + ((t&255)>>4);
  const int a3  = (t>>4)*272 + (t&15);
  const int aM  = 17*t;

  // Per-thread twiddle bases (8 scalars; redefined opaquely in-loop vs LICM).
  float s1v,c1v,s2v,c2v,s3v,c3v,psv,pcv;
  __sincosf(-6.28318530718f*(float)t/8192.f,        &s1v,&c1v);
  __sincosf(-6.28318530718f*(float)(t&255)/4096.f,  &s2v,&c2v);
  __sincosf(-6.28318530718f*(float)(t&15)/256.f,    &s3v,&c3v);
  __sincosf(-3.14159265359f*(float)t/8192.f,        &psv,&pcv);
  const float2 phstep = make_float2(0.98078528040f, -0.19509032202f);

  float breg[16];

  // --- init: b = b0 / ||b0||  (precedes spectra overwrite of brow) ----------
  {
    float nrm = 0.f;
    #pragma unroll
    for(int j=0;j<16;j++){ float v = brow[t+512*j]; breg[j]=v; nrm = fmaf(v,v,nrm); }
    #pragma unroll
    for(int off=32; off; off>>=1) nrm += __shfl_down(nrm, off, 64);
    if((t&63)==0) red[t>>6] = nrm;
    __syncthreads();
    float tot = 0.f;
    #pragma unroll
    for(int w=0;w<8;w++) tot += red[w];
    float isc = rsqrtf(tot);
    #pragma unroll
    for(int j=0;j<16;j++) breg[j] *= isc;
  }

  // --- precompute spectra (3 forward FFTs) -> global (over input rows) ------
  {
    const float2 w1 = make_float2(c1v,s1v), w2 = make_float2(c2v,s2v), w3 = make_float2(c3v,s3v);
    float fj[16], dj[16];
    #pragma unroll
    for(int j=0;j<16;j++){
      int n = t + 512*j;
      float xn = xrow[n];
      float xr = (n==0) ? 0.f : xrow[NN - n];
      fj[j] = xn + xr;
      dj[j] = xn - xr;
    }
    // FFT(f) -> 0.5*S2e at slots aM+j
    fwd_s1_real(buf, aS1, fj, w1);
    __syncthreads();
    fwd_stage16(buf, a2, 272, w2);
    __syncthreads();
    fwd_stage16(buf, a3, 17,  w3);
    __syncthreads();
    fwd_stage_last(buf, aM);
    __syncthreads();
    float se[16];
    #pragma unroll
    for(int j=0;j<16;j++) se[j] = 0.5f * buf[aM + j].x;
    __syncthreads();
    // FFT(d*phi) -> 0.5*S2o -> brow
    {
      float2 ph = make_float2(pcv, psv);
      float2 tmp[16];
      #pragma unroll
      for(int j=0;j<16;j++){ tmp[j] = make_float2(dj[j]*ph.x, dj[j]*ph.y); ph = cmul(ph, phstep); }
      fwd_s1_cplx(buf, aS1, tmp, w1);
    }
    __syncthreads();
    fwd_stage16(buf, a2, 272, w2);
    __syncthreads();
    fwd_stage16(buf, a3, 17,  w3);
    __syncthreads();
    fwd_stage_last(buf, aM);
    __syncthreads();
    #pragma unroll
    for(int j=0;j<16;j++) brow[16*t+j] = 0.5f * buf[aM + j].x;
    __syncthreads();
    // FFT(c) -> Fc; G = Fc*(1 + i*se) -> xrow/crow
    #pragma unroll
    for(int j=0;j<16;j++) fj[j] = crow[t+512*j];
    fwd_s1_real(buf, aS1, fj, w1);
    __syncthreads();
    fwd_stage16(buf, a2, 272, w2);
    __syncthreads();
    fwd_stage16(buf, a3, 17,  w3);
    __syncthreads();
    fwd_stage_last(buf, aM);
    __syncthreads();
    if (t < 256) {
      float2* gdst = (float2*)xrow;
      #pragma unroll
      for(int j=0;j<16;j++){
        int e = 16*t + j;
        float2 fc = buf[aM + j];
        gdst[e] = make_float2(fmaf(-fc.y, se[j], fc.x), fmaf(fc.x, se[j], fc.y));
      }
    } else {
      float2* gdst = (float2*)crow;
      #pragma unroll
      for(int j=0;j<16;j++){
        int e = 16*t + j;
        float2 fc = buf[aM + j];
        gdst[e - 4096] = make_float2(fmaf(-fc.y, se[j], fc.x), fmaf(fc.x, se[j], fc.y));
      }
    }
    __syncthreads();
  }

  const float4* gptr = (t < 256) ? (const float4*)((const float2*)xrow + 16*t)
                                 : (const float4*)((const float2*)crow + (16*t - 4096));
  const float4* sptr = (const float4*)(brow + 16*t);

  // --- 100 power iterations (rolled) ----------------------------------------
  #pragma clang loop unroll(disable)
  for(int iter=0; iter<100; ++iter){
    // Opaque redefinition: kills LICM hoisting/spilling of all twiddle chains.
    asm volatile("" : "+v"(c1v), "+v"(s1v), "+v"(c2v), "+v"(s2v),
                      "+v"(c3v), "+v"(s3v), "+v"(pcv), "+v"(psv));
    const float2 w1 = make_float2(c1v,s1v), w2 = make_float2(c2v,s2v), w3 = make_float2(c3v,s3v);
    float tot = iterate<false>(buf, red, t, breg, aS1, a2, a3, aM,
                               w1, w2, w3, pcv, psv, gptr, sptr);
    float s = rsqrtf(tot);
    #pragma unroll
    for(int j=0;j<16;j++) breg[j] *= s;
  }

  // --- final matvec for sigma ------------------------------------------------
  {
    asm volatile("" : "+v"(c1v), "+v"(s1v), "+v"(c2v), "+v"(s2v),
                      "+v"(c3v), "+v"(s3v), "+v"(pcv), "+v"(psv));
    const float2 w1 = make_float2(c1v,s1v), w2 = make_float2(c2v,s2v), w3 = make_float2(c3v,s3v);
    float tot = iterate<true>(buf, red, t, breg, aS1, a2, a3, aM,
                              w1, w2, w3, pcv, psv, gptr, sptr);
    if(t == 0) atomicAdd(out, fabsf(tot) * (1.f/512.f));
  }
}

extern "C" void kernel_launch(void* const* d_in, const int* in_sizes, int n_in,
                              void* d_out, int out_size, void* d_ws, size_t ws_size,
                              hipStream_t stream) {
  float* x    = (float*)d_in[0];
  float* circ = (float*)d_in[1];
  float* b0   = (float*)d_in[2];
  float* out  = (float*)d_out;

  hipLaunchKernelGGL(msvl_zero, dim3(1), dim3(1), 0, stream, out);
  hipLaunchKernelGGL(msvl_main, dim3(ROWS), dim3(NT), 0, stream,
                     x, circ, b0, out);
}